// Round 1
// baseline (185.481 us; speedup 1.0000x reference)
//
#include <hip/hip_runtime.h>
#include <stdint.h>

#define NB 8
#define NT 1024
#define ND 768
#define NH 12

static constexpr float ATT_SCALE = 0.125f;  // 64^-0.5

typedef __bf16 bf16x8 __attribute__((ext_vector_type(8)));
typedef float f32x4 __attribute__((ext_vector_type(4)));
typedef unsigned short u16;

__device__ __forceinline__ u16 f2b(float f) {
  union { float f; uint32_t u; } c; c.f = f;
  uint32_t u = c.u;
  u += 0x7fffu + ((u >> 16) & 1u);
  return (u16)(u >> 16);
}

// ---------------- cast f32 -> bf16, 4 at a time ----------------
__global__ void k_cast(const float* __restrict__ in, u16* __restrict__ out, int n4) {
  int i = blockIdx.x * blockDim.x + threadIdx.x;
  if (i >= n4) return;
  float4 v = reinterpret_cast<const float4*>(in)[i];
  ushort4 o;
  o.x = f2b(v.x); o.y = f2b(v.y); o.z = f2b(v.z); o.w = f2b(v.w);
  reinterpret_cast<ushort4*>(out)[i] = o;
}

// ---------------- transpose+cast: in[R][C] f32 -> out[C][R] bf16 ----------------
__global__ void k_tcast(const float* __restrict__ in, u16* __restrict__ out, int R, int C) {
  __shared__ float tile[32][33];
  int c0 = blockIdx.x * 32, r0 = blockIdx.y * 32;
  int tx = threadIdx.x & 31, ty = threadIdx.x >> 5;  // 256 threads: ty 0..7
  #pragma unroll
  for (int rr = ty; rr < 32; rr += 8)
    tile[rr][tx] = in[(size_t)(r0 + rr) * C + c0 + tx];
  __syncthreads();
  #pragma unroll
  for (int cc = ty; cc < 32; cc += 8)
    out[(size_t)(c0 + cc) * R + r0 + tx] = f2b(tile[tx][cc]);
}

// ---------------- QKV GEMM: [8192,768] x [768,2304] + bias ----------------
// A row-major bf16, Bt = W^T row-major bf16 ([2304][768]).
// Epilogue scatters: Q*scale -> [B,H,T,64], K -> [B,H,T,64], V -> [B,H,64,T] (transposed)
#define GBM 128
#define GBN 128
#define GBK 32
#define ASTR 40  // LDS row stride in elems (80B, 16B-aligned, non-pow2)

__launch_bounds__(256, 2)
__global__ void k_gemm_qkv(const u16* __restrict__ A, const u16* __restrict__ Bt,
                           const float* __restrict__ bias,
                           u16* __restrict__ Qg, u16* __restrict__ Kg, u16* __restrict__ Vt)
{
  __shared__ u16 Al[GBM * ASTR];
  __shared__ u16 Bl[GBN * ASTR];
  const int tid = threadIdx.x, lane = tid & 63, wv = tid >> 6;
  const int g = lane >> 4, r = lane & 15;
  const int wm = (wv >> 1) * 64, wn = (wv & 1) * 64;
  const int m0 = blockIdx.y * GBM, n0 = blockIdx.x * GBN;
  f32x4 acc[4][4] = {};
  for (int k0 = 0; k0 < ND; k0 += GBK) {
    __syncthreads();
    #pragma unroll
    for (int it = 0; it < 2; ++it) {
      int idx = tid + it * 256;
      int row = idx >> 2, c8 = (idx & 3) * 8;
      *reinterpret_cast<uint4*>(&Al[row * ASTR + c8]) =
          *reinterpret_cast<const uint4*>(&A[(size_t)(m0 + row) * ND + k0 + c8]);
      *reinterpret_cast<uint4*>(&Bl[row * ASTR + c8]) =
          *reinterpret_cast<const uint4*>(&Bt[(size_t)(n0 + row) * ND + k0 + c8]);
    }
    __syncthreads();
    bf16x8 af[4], bfr[4];
    #pragma unroll
    for (int mf = 0; mf < 4; ++mf)
      af[mf] = *reinterpret_cast<const bf16x8*>(&Al[(wm + mf * 16 + r) * ASTR + g * 8]);
    #pragma unroll
    for (int nf = 0; nf < 4; ++nf)
      bfr[nf] = *reinterpret_cast<const bf16x8*>(&Bl[(wn + nf * 16 + r) * ASTR + g * 8]);
    #pragma unroll
    for (int mf = 0; mf < 4; ++mf)
      #pragma unroll
      for (int nf = 0; nf < 4; ++nf)
        acc[mf][nf] = __builtin_amdgcn_mfma_f32_16x16x32_bf16(af[mf], bfr[nf], acc[mf][nf], 0, 0, 0);
  }
  #pragma unroll
  for (int mf = 0; mf < 4; ++mf)
    #pragma unroll
    for (int nf = 0; nf < 4; ++nf)
      #pragma unroll
      for (int jj = 0; jj < 4; ++jj) {
        int row = m0 + wm + mf * 16 + 4 * g + jj;   // [0,8192)
        int col = n0 + wn + nf * 16 + r;            // [0,2304)
        float v = acc[mf][nf][jj] + bias[col];
        int bb = row >> 10, t = row & 1023;
        int which = col / ND, c = col - which * ND;
        int h = c >> 6, hd = c & 63;
        size_t bh = (size_t)bb * NH + h;
        if (which == 0)      Qg[(bh * NT + t) * 64 + hd] = f2b(v * ATT_SCALE);
        else if (which == 1) Kg[(bh * NT + t) * 64 + hd] = f2b(v);
        else                 Vt[(bh * 64 + hd) * NT + t] = f2b(v);
      }
}

// ---------------- flash attention ----------------
// block = (qt, bh): 4 waves x 32 q-rows = 128 q-rows; KV tiles of 128.
#define KSTR 72
#define VSTR 136
#define PSTR 136

__launch_bounds__(256, 2)
__global__ void k_attn(const u16* __restrict__ Qg, const u16* __restrict__ Kg,
                       const u16* __restrict__ Vt, u16* __restrict__ Ob)
{
  __shared__ u16 Kl[128 * KSTR];
  __shared__ u16 Vl[64 * VSTR];
  __shared__ u16 Pl[4][32 * PSTR];
  const int tid = threadIdx.x, lane = tid & 63, wv = tid >> 6;
  const int g = lane >> 4, r = lane & 15;
  const int bh = blockIdx.y;  // 0..95
  const int qt = blockIdx.x;  // 0..7
  const int bb = bh / NH, h = bh - bb * NH;
  const u16* Qb = Qg + (size_t)bh * NT * 64;
  const u16* Kb = Kg + (size_t)bh * NT * 64;
  const u16* Vb = Vt + (size_t)bh * 64 * NT;

  // Q fragments held in registers for the whole kernel
  bf16x8 qf[2][2];
  #pragma unroll
  for (int mf = 0; mf < 2; ++mf)
    #pragma unroll
    for (int kk = 0; kk < 2; ++kk) {
      int qrow = qt * 128 + wv * 32 + mf * 16 + r;
      qf[mf][kk] = *reinterpret_cast<const bf16x8*>(&Qb[(size_t)qrow * 64 + kk * 32 + g * 8]);
    }

  float mst[8], lst[8];
  #pragma unroll
  for (int i = 0; i < 8; ++i) { mst[i] = -1e30f; lst[i] = 0.f; }
  f32x4 oacc[2][4] = {};

  for (int kt = 0; kt < NT / 128; ++kt) {
    __syncthreads();
    #pragma unroll
    for (int it = 0; it < 4; ++it) {
      int idx = tid + it * 256;
      { int row = idx >> 3, c8 = (idx & 7) * 8;   // K tile: 128 x 64
        *reinterpret_cast<uint4*>(&Kl[row * KSTR + c8]) =
            *reinterpret_cast<const uint4*>(&Kb[(size_t)(kt * 128 + row) * 64 + c8]); }
      { int row = idx >> 4, c8 = (idx & 15) * 8;  // V^T tile: 64 x 128
        *reinterpret_cast<uint4*>(&Vl[row * VSTR + c8]) =
            *reinterpret_cast<const uint4*>(&Vb[(size_t)row * NT + kt * 128 + c8]); }
    }
    __syncthreads();

    // S = Q K^T  (pre-scaled Q)
    f32x4 sacc[2][8] = {};
    #pragma unroll
    for (int kk = 0; kk < 2; ++kk) {
      bf16x8 kf[8];
      #pragma unroll
      for (int nf = 0; nf < 8; ++nf)
        kf[nf] = *reinterpret_cast<const bf16x8*>(&Kl[(nf * 16 + r) * KSTR + kk * 32 + g * 8]);
      #pragma unroll
      for (int mf = 0; mf < 2; ++mf)
        #pragma unroll
        for (int nf = 0; nf < 8; ++nf)
          sacc[mf][nf] = __builtin_amdgcn_mfma_f32_16x16x32_bf16(qf[mf][kk], kf[nf], sacc[mf][nf], 0, 0, 0);
    }

    // online softmax; rows live in lanes sharing g, reduce across 16 lanes (masks 1,2,4,8)
    #pragma unroll
    for (int mf = 0; mf < 2; ++mf)
      #pragma unroll
      for (int jj = 0; jj < 4; ++jj) {
        float mx = -1e30f;
        #pragma unroll
        for (int nf = 0; nf < 8; ++nf) mx = fmaxf(mx, sacc[mf][nf][jj]);
        #pragma unroll
        for (int s = 1; s < 16; s <<= 1) mx = fmaxf(mx, __shfl_xor(mx, s, 64));
        const int si = mf * 4 + jj;
        float mold = mst[si], mnew = fmaxf(mold, mx);
        float corr = __expf(mold - mnew);
        float rs = 0.f;
        #pragma unroll
        for (int nf = 0; nf < 8; ++nf) {
          float p = __expf(sacc[mf][nf][jj] - mnew);
          sacc[mf][nf][jj] = p;
          rs += p;
        }
        #pragma unroll
        for (int s = 1; s < 16; s <<= 1) rs += __shfl_xor(rs, s, 64);
        mst[si] = mnew;
        lst[si] = lst[si] * corr + rs;
        #pragma unroll
        for (int hf = 0; hf < 4; ++hf) oacc[mf][hf][jj] *= corr;
      }

    // P -> bf16 -> wave-private LDS (D-layout write, A-layout read)
    u16* Plw = Pl[wv];
    #pragma unroll
    for (int mf = 0; mf < 2; ++mf)
      #pragma unroll
      for (int nf = 0; nf < 8; ++nf)
        #pragma unroll
        for (int jj = 0; jj < 4; ++jj)
          Plw[(mf * 16 + 4 * g + jj) * PSTR + nf * 16 + r] = f2b(sacc[mf][nf][jj]);
    __syncthreads();

    // O += P V
    #pragma unroll
    for (int ks = 0; ks < 4; ++ks) {
      bf16x8 pf[2], vf[4];
      #pragma unroll
      for (int mf = 0; mf < 2; ++mf)
        pf[mf] = *reinterpret_cast<const bf16x8*>(&Plw[(mf * 16 + r) * PSTR + ks * 32 + g * 8]);
      #pragma unroll
      for (int hf = 0; hf < 4; ++hf)
        vf[hf] = *reinterpret_cast<const bf16x8*>(&Vl[(hf * 16 + r) * VSTR + ks * 32 + g * 8]);
      #pragma unroll
      for (int mf = 0; mf < 2; ++mf)
        #pragma unroll
        for (int hf = 0; hf < 4; ++hf)
          oacc[mf][hf] = __builtin_amdgcn_mfma_f32_16x16x32_bf16(pf[mf], vf[hf], oacc[mf][hf], 0, 0, 0);
    }
  }

  // normalize + store O as bf16 [B,T,H*64]
  #pragma unroll
  for (int mf = 0; mf < 2; ++mf)
    #pragma unroll
    for (int hf = 0; hf < 4; ++hf)
      #pragma unroll
      for (int jj = 0; jj < 4; ++jj) {
        int row = qt * 128 + wv * 32 + mf * 16 + 4 * g + jj;
        float v = oacc[mf][hf][jj] / lst[mf * 4 + jj];
        Ob[((size_t)(bb * NT + row)) * ND + h * 64 + hf * 16 + r] = f2b(v);
      }
}

// ---------------- proj GEMM: [8192,768] x [768,768] + bias -> f32 out ----------------
__launch_bounds__(256, 2)
__global__ void k_gemm_proj(const u16* __restrict__ A, const u16* __restrict__ Bt,
                            const float* __restrict__ bias, float* __restrict__ out)
{
  __shared__ u16 Al[GBM * ASTR];
  __shared__ u16 Bl[GBN * ASTR];
  const int tid = threadIdx.x, lane = tid & 63, wv = tid >> 6;
  const int g = lane >> 4, r = lane & 15;
  const int wm = (wv >> 1) * 64, wn = (wv & 1) * 64;
  const int m0 = blockIdx.y * GBM, n0 = blockIdx.x * GBN;
  f32x4 acc[4][4] = {};
  for (int k0 = 0; k0 < ND; k0 += GBK) {
    __syncthreads();
    #pragma unroll
    for (int it = 0; it < 2; ++it) {
      int idx = tid + it * 256;
      int row = idx >> 2, c8 = (idx & 3) * 8;
      *reinterpret_cast<uint4*>(&Al[row * ASTR + c8]) =
          *reinterpret_cast<const uint4*>(&A[(size_t)(m0 + row) * ND + k0 + c8]);
      *reinterpret_cast<uint4*>(&Bl[row * ASTR + c8]) =
          *reinterpret_cast<const uint4*>(&Bt[(size_t)(n0 + row) * ND + k0 + c8]);
    }
    __syncthreads();
    bf16x8 af[4], bfr[4];
    #pragma unroll
    for (int mf = 0; mf < 4; ++mf)
      af[mf] = *reinterpret_cast<const bf16x8*>(&Al[(wm + mf * 16 + r) * ASTR + g * 8]);
    #pragma unroll
    for (int nf = 0; nf < 4; ++nf)
      bfr[nf] = *reinterpret_cast<const bf16x8*>(&Bl[(wn + nf * 16 + r) * ASTR + g * 8]);
    #pragma unroll
    for (int mf = 0; mf < 4; ++mf)
      #pragma unroll
      for (int nf = 0; nf < 4; ++nf)
        acc[mf][nf] = __builtin_amdgcn_mfma_f32_16x16x32_bf16(af[mf], bfr[nf], acc[mf][nf], 0, 0, 0);
  }
  #pragma unroll
  for (int mf = 0; mf < 4; ++mf)
    #pragma unroll
    for (int nf = 0; nf < 4; ++nf)
      #pragma unroll
      for (int jj = 0; jj < 4; ++jj) {
        int row = m0 + wm + mf * 16 + 4 * g + jj;
        int col = n0 + wn + nf * 16 + r;
        out[(size_t)row * ND + col] = acc[mf][nf][jj] + bias[col];
      }
}

// ---------------- launch ----------------
extern "C" void kernel_launch(void* const* d_in, const int* in_sizes, int n_in,
                              void* d_out, int out_size, void* d_ws, size_t ws_size,
                              hipStream_t stream)
{
  const float* x     = (const float*)d_in[0];
  const float* Wqkv  = (const float*)d_in[1];
  const float* bqkv  = (const float*)d_in[2];
  const float* Wproj = (const float*)d_in[3];
  const float* bproj = (const float*)d_in[4];
  float* out = (float*)d_out;

  char* ws = (char*)d_ws;
  u16* xb  = (u16*)(ws + 0);          // 8192*768*2      = 12,582,912
  u16* wqt = (u16*)(ws + 12582912);   // 2304*768*2      =  3,538,944
  u16* wpt = (u16*)(ws + 16121856);   // 768*768*2       =  1,179,648
  u16* Qg  = (u16*)(ws + 17301504);   // 96*1024*64*2    = 12,582,912
  u16* Kg  = (u16*)(ws + 29884416);
  u16* Vt  = (u16*)(ws + 42467328);
  u16* Ob  = (u16*)(ws + 55050240);   // ends at 67,633,152

  k_cast<<<dim3((8192 * 768 / 4 + 255) / 256), dim3(256), 0, stream>>>(x, xb, 8192 * 768 / 4);
  k_tcast<<<dim3(2304 / 32, 768 / 32), dim3(256), 0, stream>>>(Wqkv, wqt, 768, 2304);
  k_tcast<<<dim3(768 / 32, 768 / 32), dim3(256), 0, stream>>>(Wproj, wpt, 768, 768);
  k_gemm_qkv<<<dim3(2304 / 128, 8192 / 128), dim3(256), 0, stream>>>(xb, wqt, bqkv, Qg, Kg, Vt);
  k_attn<<<dim3(8, 96), dim3(256), 0, stream>>>(Qg, Kg, Vt, Ob);
  k_gemm_proj<<<dim3(768 / 128, 8192 / 128), dim3(256), 0, stream>>>(Ob, wpt, bproj, out);
}

// Round 2
// 165.672 us; speedup vs baseline: 1.1196x; 1.1196x over previous
//
#include <hip/hip_runtime.h>
#include <stdint.h>

#define NB 8
#define NT 1024
#define ND 768
#define NH 12

static constexpr float ATT_SCALE = 0.125f;  // 64^-0.5

typedef __bf16 bf16x8 __attribute__((ext_vector_type(8)));
typedef float f32x4 __attribute__((ext_vector_type(4)));
typedef unsigned short u16;

__device__ __forceinline__ u16 f2b(float f) {
  union { float f; uint32_t u; } c; c.f = f;
  uint32_t u = c.u;
  u += 0x7fffu + ((u >> 16) & 1u);
  return (u16)(u >> 16);
}

// async global->LDS, 16B per lane; LDS dest = wave-uniform base + lane*16
__device__ __forceinline__ void gload16(const void* g, void* l) {
  __builtin_amdgcn_global_load_lds(
      (const __attribute__((address_space(1))) void*)g,
      (__attribute__((address_space(3))) void*)l, 16, 0, 0);
}

// ---------------- cast f32 -> bf16, 4 at a time ----------------
__global__ void k_cast(const float* __restrict__ in, u16* __restrict__ out, int n4) {
  int i = blockIdx.x * blockDim.x + threadIdx.x;
  if (i >= n4) return;
  float4 v = reinterpret_cast<const float4*>(in)[i];
  ushort4 o;
  o.x = f2b(v.x); o.y = f2b(v.y); o.z = f2b(v.z); o.w = f2b(v.w);
  reinterpret_cast<ushort4*>(out)[i] = o;
}

// ---------------- transpose+cast: in[R][C] f32 -> out[C][R] bf16 ----------------
__global__ void k_tcast(const float* __restrict__ in, u16* __restrict__ out, int R, int C) {
  __shared__ float tile[32][33];
  int c0 = blockIdx.x * 32, r0 = blockIdx.y * 32;
  int tx = threadIdx.x & 31, ty = threadIdx.x >> 5;  // 256 threads: ty 0..7
  #pragma unroll
  for (int rr = ty; rr < 32; rr += 8)
    tile[rr][tx] = in[(size_t)(r0 + rr) * C + c0 + tx];
  __syncthreads();
  #pragma unroll
  for (int cc = ty; cc < 32; cc += 8)
    out[(size_t)(c0 + cc) * R + r0 + tx] = f2b(tile[tx][cc]);
}

// ---------------- QKV GEMM: [8192,768] x [768,2304] + bias ----------------
// m97 structure: 128x128 tile, BK=32, linear LDS, global_load_lds width 16.
// Epilogue scatters: Q*scale -> [B,H,T,64], K -> [B,H,T,64], V -> [B,H,64,T] (transposed)
__launch_bounds__(256, 3)
__global__ void k_gemm_qkv(const u16* __restrict__ A, const u16* __restrict__ Bt,
                           const float* __restrict__ bias,
                           u16* __restrict__ Qg, u16* __restrict__ Kg, u16* __restrict__ Vt)
{
  __shared__ u16 Al[128 * 32];
  __shared__ u16 Bl[128 * 32];
  const int tid = threadIdx.x, lane = tid & 63, wv = tid >> 6;
  const int g = lane >> 4, r = lane & 15;
  const int wm = (wv >> 1) * 64, wn = (wv & 1) * 64;
  const int m0 = blockIdx.y * 128, n0 = blockIdx.x * 128;
  const int srow = lane >> 2;        // row within 16-row chunk
  const int scol = (lane & 3) * 8;   // elem col within 32-elem row
  f32x4 acc[4][4] = {};
  for (int k0 = 0; k0 < ND; k0 += 32) {
    __syncthreads();
    #pragma unroll
    for (int i = 0; i < 2; ++i) {
      int c = wv * 2 + i;  // 1KB chunk id = 16 rows
      gload16(&A[(size_t)(m0 + c * 16 + srow) * ND + k0 + scol], &Al[c * 512]);
      gload16(&Bt[(size_t)(n0 + c * 16 + srow) * ND + k0 + scol], &Bl[c * 512]);
    }
    __syncthreads();
    bf16x8 af[4], bfr[4];
    #pragma unroll
    for (int mf = 0; mf < 4; ++mf)
      af[mf] = *reinterpret_cast<const bf16x8*>(&Al[(wm + mf * 16 + r) * 32 + g * 8]);
    #pragma unroll
    for (int nf = 0; nf < 4; ++nf)
      bfr[nf] = *reinterpret_cast<const bf16x8*>(&Bl[(wn + nf * 16 + r) * 32 + g * 8]);
    #pragma unroll
    for (int mf = 0; mf < 4; ++mf)
      #pragma unroll
      for (int nf = 0; nf < 4; ++nf)
        acc[mf][nf] = __builtin_amdgcn_mfma_f32_16x16x32_bf16(af[mf], bfr[nf], acc[mf][nf], 0, 0, 0);
  }
  #pragma unroll
  for (int mf = 0; mf < 4; ++mf)
    #pragma unroll
    for (int nf = 0; nf < 4; ++nf) {
      int col = n0 + wn + nf * 16 + r;         // [0,2304)
      int which = col / ND, c = col - which * ND;  // uniform per fragment (768 % 16 == 0)
      int h = c >> 6, hd = c & 63;
      int row0 = m0 + wm + mf * 16 + 4 * g;    // 4 consecutive t values
      int bb = row0 >> 10, t0 = row0 & 1023;
      size_t bh = (size_t)bb * NH + h;
      float b = bias[col];
      if (which == 2) {
        ushort4 o;
        o.x = f2b(acc[mf][nf][0] + b);
        o.y = f2b(acc[mf][nf][1] + b);
        o.z = f2b(acc[mf][nf][2] + b);
        o.w = f2b(acc[mf][nf][3] + b);
        *reinterpret_cast<ushort4*>(&Vt[(bh * 64 + hd) * NT + t0]) = o;
      } else if (which == 0) {
        #pragma unroll
        for (int jj = 0; jj < 4; ++jj)
          Qg[(bh * NT + t0 + jj) * 64 + hd] = f2b((acc[mf][nf][jj] + b) * ATT_SCALE);
      } else {
        #pragma unroll
        for (int jj = 0; jj < 4; ++jj)
          Kg[(bh * NT + t0 + jj) * 64 + hd] = f2b(acc[mf][nf][jj] + b);
      }
    }
}

// ---------------- flash attention ----------------
// block = (qt, bh): 4 waves x 32 q-rows = 128 q-rows; KV tiles of 128.
#define KSTR 72
#define VSTR 136
#define PSTR 136

__launch_bounds__(256, 2)
__global__ void k_attn(const u16* __restrict__ Qg, const u16* __restrict__ Kg,
                       const u16* __restrict__ Vt, u16* __restrict__ Ob)
{
  __shared__ u16 Kl[128 * KSTR];
  __shared__ u16 Vl[64 * VSTR];
  __shared__ u16 Pl[4][32 * PSTR];
  const int tid = threadIdx.x, lane = tid & 63, wv = tid >> 6;
  const int g = lane >> 4, r = lane & 15;
  const int bh = blockIdx.y;  // 0..95
  const int qt = blockIdx.x;  // 0..7
  const int bb = bh / NH, h = bh - bb * NH;
  const u16* Qb = Qg + (size_t)bh * NT * 64;
  const u16* Kb = Kg + (size_t)bh * NT * 64;
  const u16* Vb = Vt + (size_t)bh * 64 * NT;

  // Q fragments held in registers for the whole kernel
  bf16x8 qf[2][2];
  #pragma unroll
  for (int mf = 0; mf < 2; ++mf)
    #pragma unroll
    for (int kk = 0; kk < 2; ++kk) {
      int qrow = qt * 128 + wv * 32 + mf * 16 + r;
      qf[mf][kk] = *reinterpret_cast<const bf16x8*>(&Qb[(size_t)qrow * 64 + kk * 32 + g * 8]);
    }

  float mst[8], lst[8];
  #pragma unroll
  for (int i = 0; i < 8; ++i) { mst[i] = -1e30f; lst[i] = 0.f; }
  f32x4 oacc[2][4] = {};

  for (int kt = 0; kt < NT / 128; ++kt) {
    __syncthreads();
    #pragma unroll
    for (int it = 0; it < 4; ++it) {
      int idx = tid + it * 256;
      { int row = idx >> 3, c8 = (idx & 7) * 8;   // K tile: 128 x 64
        *reinterpret_cast<uint4*>(&Kl[row * KSTR + c8]) =
            *reinterpret_cast<const uint4*>(&Kb[(size_t)(kt * 128 + row) * 64 + c8]); }
      { int row = idx >> 4, c8 = (idx & 15) * 8;  // V^T tile: 64 x 128
        *reinterpret_cast<uint4*>(&Vl[row * VSTR + c8]) =
            *reinterpret_cast<const uint4*>(&Vb[(size_t)row * NT + kt * 128 + c8]); }
    }
    __syncthreads();

    // S = Q K^T  (pre-scaled Q)
    f32x4 sacc[2][8] = {};
    #pragma unroll
    for (int kk = 0; kk < 2; ++kk) {
      bf16x8 kf[8];
      #pragma unroll
      for (int nf = 0; nf < 8; ++nf)
        kf[nf] = *reinterpret_cast<const bf16x8*>(&Kl[(nf * 16 + r) * KSTR + kk * 32 + g * 8]);
      #pragma unroll
      for (int mf = 0; mf < 2; ++mf)
        #pragma unroll
        for (int nf = 0; nf < 8; ++nf)
          sacc[mf][nf] = __builtin_amdgcn_mfma_f32_16x16x32_bf16(qf[mf][kk], kf[nf], sacc[mf][nf], 0, 0, 0);
    }

    // online softmax; rows live in lanes sharing g, reduce across 16 lanes
    #pragma unroll
    for (int mf = 0; mf < 2; ++mf)
      #pragma unroll
      for (int jj = 0; jj < 4; ++jj) {
        float mx = -1e30f;
        #pragma unroll
        for (int nf = 0; nf < 8; ++nf) mx = fmaxf(mx, sacc[mf][nf][jj]);
        #pragma unroll
        for (int s = 1; s < 16; s <<= 1) mx = fmaxf(mx, __shfl_xor(mx, s, 64));
        const int si = mf * 4 + jj;
        float mold = mst[si], mnew = fmaxf(mold, mx);
        float corr = __expf(mold - mnew);
        float rs = 0.f;
        #pragma unroll
        for (int nf = 0; nf < 8; ++nf) {
          float p = __expf(sacc[mf][nf][jj] - mnew);
          sacc[mf][nf][jj] = p;
          rs += p;
        }
        #pragma unroll
        for (int s = 1; s < 16; s <<= 1) rs += __shfl_xor(rs, s, 64);
        mst[si] = mnew;
        lst[si] = lst[si] * corr + rs;
        #pragma unroll
        for (int hf = 0; hf < 4; ++hf) oacc[mf][hf][jj] *= corr;
      }

    // P -> bf16 -> wave-private LDS (D-layout write, A-layout read)
    u16* Plw = Pl[wv];
    #pragma unroll
    for (int mf = 0; mf < 2; ++mf)
      #pragma unroll
      for (int nf = 0; nf < 8; ++nf)
        #pragma unroll
        for (int jj = 0; jj < 4; ++jj)
          Plw[(mf * 16 + 4 * g + jj) * PSTR + nf * 16 + r] = f2b(sacc[mf][nf][jj]);
    __syncthreads();

    // O += P V
    #pragma unroll
    for (int ks = 0; ks < 4; ++ks) {
      bf16x8 pf[2], vf[4];
      #pragma unroll
      for (int mf = 0; mf < 2; ++mf)
        pf[mf] = *reinterpret_cast<const bf16x8*>(&Plw[(mf * 16 + r) * PSTR + ks * 32 + g * 8]);
      #pragma unroll
      for (int hf = 0; hf < 4; ++hf)
        vf[hf] = *reinterpret_cast<const bf16x8*>(&Vl[(hf * 16 + r) * VSTR + ks * 32 + g * 8]);
      #pragma unroll
      for (int mf = 0; mf < 2; ++mf)
        #pragma unroll
        for (int hf = 0; hf < 4; ++hf)
          oacc[mf][hf] = __builtin_amdgcn_mfma_f32_16x16x32_bf16(pf[mf], vf[hf], oacc[mf][hf], 0, 0, 0);
    }
  }

  // normalize + store O as bf16 [B,T,H*64]
  #pragma unroll
  for (int mf = 0; mf < 2; ++mf)
    #pragma unroll
    for (int hf = 0; hf < 4; ++hf)
      #pragma unroll
      for (int jj = 0; jj < 4; ++jj) {
        int row = qt * 128 + wv * 32 + mf * 16 + 4 * g + jj;
        float v = oacc[mf][hf][jj] / lst[mf * 4 + jj];
        Ob[((size_t)(bb * NT + row)) * ND + h * 64 + hf * 16 + r] = f2b(v);
      }
}

// ---------------- proj GEMM: [8192,768] x [768,768] + bias -> f32 out ----------------
__launch_bounds__(256, 3)
__global__ void k_gemm_proj(const u16* __restrict__ A, const u16* __restrict__ Bt,
                            const float* __restrict__ bias, float* __restrict__ out)
{
  __shared__ u16 Al[128 * 32];
  __shared__ u16 Bl[128 * 32];
  const int tid = threadIdx.x, lane = tid & 63, wv = tid >> 6;
  const int g = lane >> 4, r = lane & 15;
  const int wm = (wv >> 1) * 64, wn = (wv & 1) * 64;
  const int m0 = blockIdx.y * 128, n0 = blockIdx.x * 128;
  const int srow = lane >> 2;
  const int scol = (lane & 3) * 8;
  f32x4 acc[4][4] = {};
  for (int k0 = 0; k0 < ND; k0 += 32) {
    __syncthreads();
    #pragma unroll
    for (int i = 0; i < 2; ++i) {
      int c = wv * 2 + i;
      gload16(&A[(size_t)(m0 + c * 16 + srow) * ND + k0 + scol], &Al[c * 512]);
      gload16(&Bt[(size_t)(n0 + c * 16 + srow) * ND + k0 + scol], &Bl[c * 512]);
    }
    __syncthreads();
    bf16x8 af[4], bfr[4];
    #pragma unroll
    for (int mf = 0; mf < 4; ++mf)
      af[mf] = *reinterpret_cast<const bf16x8*>(&Al[(wm + mf * 16 + r) * 32 + g * 8]);
    #pragma unroll
    for (int nf = 0; nf < 4; ++nf)
      bfr[nf] = *reinterpret_cast<const bf16x8*>(&Bl[(wn + nf * 16 + r) * 32 + g * 8]);
    #pragma unroll
    for (int mf = 0; mf < 4; ++mf)
      #pragma unroll
      for (int nf = 0; nf < 4; ++nf)
        acc[mf][nf] = __builtin_amdgcn_mfma_f32_16x16x32_bf16(af[mf], bfr[nf], acc[mf][nf], 0, 0, 0);
  }
  #pragma unroll
  for (int mf = 0; mf < 4; ++mf)
    #pragma unroll
    for (int nf = 0; nf < 4; ++nf) {
      int col = n0 + wn + nf * 16 + r;
      float b = bias[col];
      #pragma unroll
      for (int jj = 0; jj < 4; ++jj) {
        int row = m0 + wm + mf * 16 + 4 * g + jj;
        out[(size_t)row * ND + col] = acc[mf][nf][jj] + b;
      }
    }
}

// ---------------- launch ----------------
extern "C" void kernel_launch(void* const* d_in, const int* in_sizes, int n_in,
                              void* d_out, int out_size, void* d_ws, size_t ws_size,
                              hipStream_t stream)
{
  const float* x     = (const float*)d_in[0];
  const float* Wqkv  = (const float*)d_in[1];
  const float* bqkv  = (const float*)d_in[2];
  const float* Wproj = (const float*)d_in[3];
  const float* bproj = (const float*)d_in[4];
  float* out = (float*)d_out;

  char* ws = (char*)d_ws;
  u16* xb  = (u16*)(ws + 0);          // 8192*768*2      = 12,582,912
  u16* wqt = (u16*)(ws + 12582912);   // 2304*768*2      =  3,538,944
  u16* wpt = (u16*)(ws + 16121856);   // 768*768*2       =  1,179,648
  u16* Qg  = (u16*)(ws + 17301504);   // 96*1024*64*2    = 12,582,912
  u16* Kg  = (u16*)(ws + 29884416);
  u16* Vt  = (u16*)(ws + 42467328);
  u16* Ob  = (u16*)(ws + 55050240);   // ends at 67,633,152

  k_cast<<<dim3((8192 * 768 / 4 + 255) / 256), dim3(256), 0, stream>>>(x, xb, 8192 * 768 / 4);
  k_tcast<<<dim3(2304 / 32, 768 / 32), dim3(256), 0, stream>>>(Wqkv, wqt, 768, 2304);
  k_tcast<<<dim3(768 / 32, 768 / 32), dim3(256), 0, stream>>>(Wproj, wpt, 768, 768);
  k_gemm_qkv<<<dim3(2304 / 128, 8192 / 128), dim3(256), 0, stream>>>(xb, wqt, bqkv, Qg, Kg, Vt);
  k_attn<<<dim3(8, 96), dim3(256), 0, stream>>>(Qg, Kg, Vt, Ob);
  k_gemm_proj<<<dim3(768 / 128, 8192 / 128), dim3(256), 0, stream>>>(Ob, wpt, bproj, out);
}

// Round 3
// 158.792 us; speedup vs baseline: 1.1681x; 1.0433x over previous
//
#include <hip/hip_runtime.h>
#include <hip/hip_bf16.h>
#include <stdint.h>

#define NB 8
#define NT 1024
#define ND 768
#define NH 12

static constexpr float ATT_SCALE = 0.125f;  // 64^-0.5

typedef __bf16 bf16x8 __attribute__((ext_vector_type(8)));
typedef float f32x4 __attribute__((ext_vector_type(4)));
typedef unsigned short u16;

__device__ __forceinline__ u16 f2b(float f) {
  union { float f; uint32_t u; } c; c.f = f;
  uint32_t u = c.u;
  u += 0x7fffu + ((u >> 16) & 1u);
  return (u16)(u >> 16);
}

// pack 2 f32 -> 2 bf16 in one u32 (compiler emits cvt_pk / cvt pair)
__device__ __forceinline__ uint32_t pk2(float a, float b) {
  __hip_bfloat162 p = __float22bfloat162_rn(make_float2(a, b));
  return *reinterpret_cast<uint32_t*>(&p);
}

// async global->LDS, 16B per lane; LDS dest = wave-uniform base + lane*16
__device__ __forceinline__ void gload16(const void* g, void* l) {
  __builtin_amdgcn_global_load_lds(
      (const __attribute__((address_space(1))) void*)g,
      (__attribute__((address_space(3))) void*)l, 16, 0, 0);
}

// ---------------- cast f32 -> bf16, 4 at a time ----------------
__global__ void k_cast(const float* __restrict__ in, u16* __restrict__ out, int n4) {
  int i = blockIdx.x * blockDim.x + threadIdx.x;
  if (i >= n4) return;
  float4 v = reinterpret_cast<const float4*>(in)[i];
  ushort4 o;
  o.x = f2b(v.x); o.y = f2b(v.y); o.z = f2b(v.z); o.w = f2b(v.w);
  reinterpret_cast<ushort4*>(out)[i] = o;
}

// ---------------- transpose+cast: in[R][C] f32 -> out[C][R] bf16 ----------------
__global__ void k_tcast(const float* __restrict__ in, u16* __restrict__ out, int R, int C) {
  __shared__ float tile[32][33];
  int c0 = blockIdx.x * 32, r0 = blockIdx.y * 32;
  int tx = threadIdx.x & 31, ty = threadIdx.x >> 5;  // 256 threads: ty 0..7
  #pragma unroll
  for (int rr = ty; rr < 32; rr += 8)
    tile[rr][tx] = in[(size_t)(r0 + rr) * C + c0 + tx];
  __syncthreads();
  #pragma unroll
  for (int cc = ty; cc < 32; cc += 8)
    out[(size_t)(c0 + cc) * R + r0 + tx] = f2b(tile[tx][cc]);
}

// ---------------- QKV GEMM: [8192,768] x [768,2304] + bias ----------------
// m97 structure + bijective XCD swizzle. Epilogue scatters Q*scale/K/V^T.
__launch_bounds__(256, 3)
__global__ void k_gemm_qkv(const u16* __restrict__ A, const u16* __restrict__ Bt,
                           const float* __restrict__ bias,
                           u16* __restrict__ Qg, u16* __restrict__ Kg, u16* __restrict__ Vt)
{
  __shared__ u16 Al[128 * 32];
  __shared__ u16 Bl[128 * 32];
  const int tid = threadIdx.x, lane = tid & 63, wv = tid >> 6;
  const int g = lane >> 4, r = lane & 15;
  const int wm = (wv >> 1) * 64, wn = (wv & 1) * 64;
  // bijective XCD swizzle: nwg = 18*64 = 1152, 1152/8 = 144
  const int bid = blockIdx.x + blockIdx.y * 18;
  const int swz = (bid & 7) * 144 + (bid >> 3);
  const int m0 = (swz / 18) * 128, n0 = (swz % 18) * 128;
  const int srow = lane >> 2;        // row within 16-row chunk
  const int scol = (lane & 3) * 8;   // elem col within 32-elem row
  f32x4 acc[4][4] = {};
  for (int k0 = 0; k0 < ND; k0 += 32) {
    __syncthreads();
    #pragma unroll
    for (int i = 0; i < 2; ++i) {
      int c = wv * 2 + i;  // 1KB chunk id = 16 rows
      gload16(&A[(size_t)(m0 + c * 16 + srow) * ND + k0 + scol], &Al[c * 512]);
      gload16(&Bt[(size_t)(n0 + c * 16 + srow) * ND + k0 + scol], &Bl[c * 512]);
    }
    __syncthreads();
    bf16x8 af[4], bfr[4];
    #pragma unroll
    for (int mf = 0; mf < 4; ++mf)
      af[mf] = *reinterpret_cast<const bf16x8*>(&Al[(wm + mf * 16 + r) * 32 + g * 8]);
    #pragma unroll
    for (int nf = 0; nf < 4; ++nf)
      bfr[nf] = *reinterpret_cast<const bf16x8*>(&Bl[(wn + nf * 16 + r) * 32 + g * 8]);
    #pragma unroll
    for (int mf = 0; mf < 4; ++mf)
      #pragma unroll
      for (int nf = 0; nf < 4; ++nf)
        acc[mf][nf] = __builtin_amdgcn_mfma_f32_16x16x32_bf16(af[mf], bfr[nf], acc[mf][nf], 0, 0, 0);
  }
  #pragma unroll
  for (int mf = 0; mf < 4; ++mf)
    #pragma unroll
    for (int nf = 0; nf < 4; ++nf) {
      int col = n0 + wn + nf * 16 + r;             // [0,2304)
      int which = col / ND, c = col - which * ND;  // uniform per fragment
      int h = c >> 6, hd = c & 63;
      int row0 = m0 + wm + mf * 16 + 4 * g;        // 4 consecutive t values
      int bb = row0 >> 10, t0 = row0 & 1023;
      size_t bh = (size_t)bb * NH + h;
      float b = bias[col];
      if (which == 2) {
        ushort4 o;
        o.x = f2b(acc[mf][nf][0] + b);
        o.y = f2b(acc[mf][nf][1] + b);
        o.z = f2b(acc[mf][nf][2] + b);
        o.w = f2b(acc[mf][nf][3] + b);
        *reinterpret_cast<ushort4*>(&Vt[(bh * 64 + hd) * NT + t0]) = o;
      } else if (which == 0) {
        #pragma unroll
        for (int jj = 0; jj < 4; ++jj)
          Qg[(bh * NT + t0 + jj) * 64 + hd] = f2b((acc[mf][nf][jj] + b) * ATT_SCALE);
      } else {
        #pragma unroll
        for (int jj = 0; jj < 4; ++jj)
          Kg[(bh * NT + t0 + jj) * 64 + hd] = f2b(acc[mf][nf][jj] + b);
      }
    }
}

// ---------------- flash attention (swapped-operand, transposed-D) ----------------
// block = (bh, qt): 4 waves x 32 q-rows; KV tiles of 128.
// S^T = mfma(K, Q): lane (g,r) holds S[k = nf*16+4g+jj][q = mf*16+r]  -> row-softmax lane-local-ish
// O^T = mfma(V^T, P^T): lane (g,r) holds O[q = mf*16+r][hd = hf*16+4g+jj]
#define KSTR 72
#define VSTR 136
#define PSTR 68

__launch_bounds__(256, 3)
__global__ void k_attn(const u16* __restrict__ Qg, const u16* __restrict__ Kg,
                       const u16* __restrict__ Vt, u16* __restrict__ Ob)
{
  __shared__ u16 Kl[128 * KSTR];
  __shared__ u16 Vl[64 * VSTR];
  __shared__ u16 Pl[4][32 * PSTR];
  const int tid = threadIdx.x, lane = tid & 63, wv = tid >> 6;
  const int g = lane >> 4, r = lane & 15;
  const int bh = blockIdx.x;  // 0..95  (fastest -> all qt of a bh share an XCD)
  const int qt = blockIdx.y;  // 0..7
  const int bb = bh / NH, h = bh - bb * NH;
  const u16* Qb = Qg + (size_t)bh * NT * 64;
  const u16* Kb = Kg + (size_t)bh * NT * 64;
  const u16* Vb = Vt + (size_t)bh * 64 * NT;

  // Q as B-fragment (Q^T): same per-lane layout as an A-load from row-major [t][64]
  bf16x8 qf[2][2];
  #pragma unroll
  for (int mf = 0; mf < 2; ++mf)
    #pragma unroll
    for (int kk = 0; kk < 2; ++kk) {
      int qrow = qt * 128 + wv * 32 + mf * 16 + r;
      qf[mf][kk] = *reinterpret_cast<const bf16x8*>(&Qb[(size_t)qrow * 64 + kk * 32 + g * 8]);
    }

  float mst[2] = {-1e30f, -1e30f}, lst[2] = {0.f, 0.f};
  f32x4 oacc[2][4] = {};  // O^T frags: [mf q-block][hf hd-block]

  for (int kt = 0; kt < NT / 128; ++kt) {
    __syncthreads();
    #pragma unroll
    for (int it = 0; it < 4; ++it) {
      int idx = tid + it * 256;
      { int row = idx >> 3, c8 = (idx & 7) * 8;   // K tile: 128 x 64
        *reinterpret_cast<uint4*>(&Kl[row * KSTR + c8]) =
            *reinterpret_cast<const uint4*>(&Kb[(size_t)(kt * 128 + row) * 64 + c8]); }
      { int row = idx >> 4, c8 = (idx & 15) * 8;  // V^T tile: 64 x 128
        *reinterpret_cast<uint4*>(&Vl[row * VSTR + c8]) =
            *reinterpret_cast<const uint4*>(&Vb[(size_t)row * NT + kt * 128 + c8]); }
    }
    __syncthreads();

    // S^T = K . Q^T   (Q pre-scaled)
    f32x4 st[2][8] = {};
    #pragma unroll
    for (int kk = 0; kk < 2; ++kk) {
      bf16x8 kf[8];
      #pragma unroll
      for (int nf = 0; nf < 8; ++nf)
        kf[nf] = *reinterpret_cast<const bf16x8*>(&Kl[(nf * 16 + r) * KSTR + kk * 32 + g * 8]);
      #pragma unroll
      for (int mf = 0; mf < 2; ++mf)
        #pragma unroll
        for (int nf = 0; nf < 8; ++nf)
          st[mf][nf] = __builtin_amdgcn_mfma_f32_16x16x32_bf16(kf[nf], qf[mf][kk], st[mf][nf], 0, 0, 0);
    }

    // online softmax: q = mf*16 + r; this lane holds 32 of the 128 k-values,
    // the rest live in lanes r, r^16, r^32, r^48 (the 4 g-groups).
    #pragma unroll
    for (int mf = 0; mf < 2; ++mf) {
      float m4[8];
      #pragma unroll
      for (int nf = 0; nf < 8; ++nf)
        m4[nf] = fmaxf(fmaxf(st[mf][nf][0], st[mf][nf][1]),
                       fmaxf(st[mf][nf][2], st[mf][nf][3]));
      float mx = fmaxf(fmaxf(fmaxf(m4[0], m4[1]), fmaxf(m4[2], m4[3])),
                       fmaxf(fmaxf(m4[4], m4[5]), fmaxf(m4[6], m4[7])));
      mx = fmaxf(mx, __shfl_xor(mx, 16, 64));
      mx = fmaxf(mx, __shfl_xor(mx, 32, 64));
      float mnew = fmaxf(mst[mf], mx);
      float corr = __expf(mst[mf] - mnew);
      float rs = 0.f;
      #pragma unroll
      for (int nf = 0; nf < 8; ++nf)
        #pragma unroll
        for (int jj = 0; jj < 4; ++jj) {
          float p = __expf(st[mf][nf][jj] - mnew);
          st[mf][nf][jj] = p;
          rs += p;
        }
      rs += __shfl_xor(rs, 16, 64);
      rs += __shfl_xor(rs, 32, 64);
      mst[mf] = mnew;
      lst[mf] = lst[mf] * corr + rs;
      #pragma unroll
      for (int hf = 0; hf < 4; ++hf) oacc[mf][hf] *= corr;  // corr is lane-local (q=r)
    }

    // P (bf16) through half-size wave-private LDS ping buffer; O^T += V^T . P^T
    u16* Plw = Pl[wv];
    #pragma unroll
    for (int half = 0; half < 2; ++half) {
      #pragma unroll
      for (int mf = 0; mf < 2; ++mf)
        #pragma unroll
        for (int nfl = 0; nfl < 4; ++nfl) {
          int nf = half * 4 + nfl;
          uint2 w;
          w.x = pk2(st[mf][nf][0], st[mf][nf][1]);
          w.y = pk2(st[mf][nf][2], st[mf][nf][3]);
          // P[q][k]: row q = mf*16+r, cols k-local = nfl*16 + 4g .. +3  (8B store)
          *reinterpret_cast<uint2*>(&Plw[(mf * 16 + r) * PSTR + nfl * 16 + 4 * g]) = w;
        }
      #pragma unroll
      for (int ks2 = 0; ks2 < 2; ++ks2) {
        int ks = half * 2 + ks2;
        bf16x8 vf[4], pf[2];
        #pragma unroll
        for (int hf = 0; hf < 4; ++hf)
          vf[hf] = *reinterpret_cast<const bf16x8*>(&Vl[(hf * 16 + r) * VSTR + ks * 32 + g * 8]);
        #pragma unroll
        for (int mf = 0; mf < 2; ++mf)
          pf[mf] = *reinterpret_cast<const bf16x8*>(&Plw[(mf * 16 + r) * PSTR + ks2 * 32 + g * 8]);
        #pragma unroll
        for (int mf = 0; mf < 2; ++mf)
          #pragma unroll
          for (int hf = 0; hf < 4; ++hf)
            oacc[mf][hf] = __builtin_amdgcn_mfma_f32_16x16x32_bf16(vf[hf], pf[mf], oacc[mf][hf], 0, 0, 0);
      }
    }
  }

  // normalize + store O as bf16 [B,T,H*64]; lane (g,r): q = mf*16+r, hd = hf*16+4g+jj
  #pragma unroll
  for (int mf = 0; mf < 2; ++mf) {
    float inv = 1.f / lst[mf];
    int row = qt * 128 + wv * 32 + mf * 16 + r;
    #pragma unroll
    for (int hf = 0; hf < 4; ++hf) {
      uint2 w;
      w.x = pk2(oacc[mf][hf][0] * inv, oacc[mf][hf][1] * inv);
      w.y = pk2(oacc[mf][hf][2] * inv, oacc[mf][hf][3] * inv);
      *reinterpret_cast<uint2*>(&Ob[((size_t)(bb * NT + row)) * ND + h * 64 + hf * 16 + 4 * g]) = w;
    }
  }
}

// ---------------- proj GEMM: [8192,768] x [768,768] + bias -> f32 out ----------------
__launch_bounds__(256, 3)
__global__ void k_gemm_proj(const u16* __restrict__ A, const u16* __restrict__ Bt,
                            const float* __restrict__ bias, float* __restrict__ out)
{
  __shared__ u16 Al[128 * 32];
  __shared__ u16 Bl[128 * 32];
  const int tid = threadIdx.x, lane = tid & 63, wv = tid >> 6;
  const int g = lane >> 4, r = lane & 15;
  const int wm = (wv >> 1) * 64, wn = (wv & 1) * 64;
  // bijective XCD swizzle: nwg = 6*64 = 384, 384/8 = 48
  const int bid = blockIdx.x + blockIdx.y * 6;
  const int swz = (bid & 7) * 48 + (bid >> 3);
  const int m0 = (swz / 6) * 128, n0 = (swz % 6) * 128;
  const int srow = lane >> 2;
  const int scol = (lane & 3) * 8;
  f32x4 acc[4][4] = {};
  for (int k0 = 0; k0 < ND; k0 += 32) {
    __syncthreads();
    #pragma unroll
    for (int i = 0; i < 2; ++i) {
      int c = wv * 2 + i;
      gload16(&A[(size_t)(m0 + c * 16 + srow) * ND + k0 + scol], &Al[c * 512]);
      gload16(&Bt[(size_t)(n0 + c * 16 + srow) * ND + k0 + scol], &Bl[c * 512]);
    }
    __syncthreads();
    bf16x8 af[4], bfr[4];
    #pragma unroll
    for (int mf = 0; mf < 4; ++mf)
      af[mf] = *reinterpret_cast<const bf16x8*>(&Al[(wm + mf * 16 + r) * 32 + g * 8]);
    #pragma unroll
    for (int nf = 0; nf < 4; ++nf)
      bfr[nf] = *reinterpret_cast<const bf16x8*>(&Bl[(wn + nf * 16 + r) * 32 + g * 8]);
    #pragma unroll
    for (int mf = 0; mf < 4; ++mf)
      #pragma unroll
      for (int nf = 0; nf < 4; ++nf)
        acc[mf][nf] = __builtin_amdgcn_mfma_f32_16x16x32_bf16(af[mf], bfr[nf], acc[mf][nf], 0, 0, 0);
  }
  #pragma unroll
  for (int mf = 0; mf < 4; ++mf)
    #pragma unroll
    for (int nf = 0; nf < 4; ++nf) {
      int col = n0 + wn + nf * 16 + r;
      float b = bias[col];
      #pragma unroll
      for (int jj = 0; jj < 4; ++jj) {
        int row = m0 + wm + mf * 16 + 4 * g + jj;
        out[(size_t)row * ND + col] = acc[mf][nf][jj] + b;
      }
    }
}

// ---------------- launch ----------------
extern "C" void kernel_launch(void* const* d_in, const int* in_sizes, int n_in,
                              void* d_out, int out_size, void* d_ws, size_t ws_size,
                              hipStream_t stream)
{
  const float* x     = (const float*)d_in[0];
  const float* Wqkv  = (const float*)d_in[1];
  const float* bqkv  = (const float*)d_in[2];
  const float* Wproj = (const float*)d_in[3];
  const float* bproj = (const float*)d_in[4];
  float* out = (float*)d_out;

  char* ws = (char*)d_ws;
  u16* xb  = (u16*)(ws + 0);          // 8192*768*2      = 12,582,912
  u16* wqt = (u16*)(ws + 12582912);   // 2304*768*2      =  3,538,944
  u16* wpt = (u16*)(ws + 16121856);   // 768*768*2       =  1,179,648
  u16* Qg  = (u16*)(ws + 17301504);   // 96*1024*64*2    = 12,582,912
  u16* Kg  = (u16*)(ws + 29884416);
  u16* Vt  = (u16*)(ws + 42467328);
  u16* Ob  = (u16*)(ws + 55050240);   // ends at 67,633,152

  k_cast<<<dim3((8192 * 768 / 4 + 255) / 256), dim3(256), 0, stream>>>(x, xb, 8192 * 768 / 4);
  k_tcast<<<dim3(2304 / 32, 768 / 32), dim3(256), 0, stream>>>(Wqkv, wqt, 768, 2304);
  k_tcast<<<dim3(768 / 32, 768 / 32), dim3(256), 0, stream>>>(Wproj, wpt, 768, 768);
  k_gemm_qkv<<<dim3(2304 / 128, 8192 / 128), dim3(256), 0, stream>>>(xb, wqt, bqkv, Qg, Kg, Vt);
  k_attn<<<dim3(96, 8), dim3(256), 0, stream>>>(Qg, Kg, Vt, Ob);
  k_gemm_proj<<<dim3(768 / 128, 8192 / 128), dim3(256), 0, stream>>>(Ob, wpt, bproj, out);
}

// Round 4
// 135.229 us; speedup vs baseline: 1.3716x; 1.1742x over previous
//
#include <hip/hip_runtime.h>
#include <hip/hip_bf16.h>
#include <stdint.h>

#define NB 8
#define NT 1024
#define ND 768
#define NH 12

static constexpr float ATT_SCALE = 0.125f;  // 64^-0.5

typedef __bf16 bf16x8 __attribute__((ext_vector_type(8)));
typedef float f32x4 __attribute__((ext_vector_type(4)));
typedef unsigned short u16;

__device__ __forceinline__ u16 f2b(float f) {
  union { float f; uint32_t u; } c; c.f = f;
  uint32_t u = c.u;
  u += 0x7fffu + ((u >> 16) & 1u);
  return (u16)(u >> 16);
}

__device__ __forceinline__ uint32_t pk2(float a, float b) {
  __hip_bfloat162 p = __float22bfloat162_rn(make_float2(a, b));
  return *reinterpret_cast<uint32_t*>(&p);
}

// async global->LDS, 16B per lane; LDS dest = wave-uniform base + lane*16
__device__ __forceinline__ void gload16(const void* g, void* l) {
  __builtin_amdgcn_global_load_lds(
      (const __attribute__((address_space(1))) void*)g,
      (__attribute__((address_space(3))) void*)l, 16, 0, 0);
}

// ---------------- cast f32 -> bf16, 4 at a time ----------------
__global__ void k_cast(const float* __restrict__ in, u16* __restrict__ out, int n4) {
  int i = blockIdx.x * blockDim.x + threadIdx.x;
  if (i >= n4) return;
  float4 v = reinterpret_cast<const float4*>(in)[i];
  ushort4 o;
  o.x = f2b(v.x); o.y = f2b(v.y); o.z = f2b(v.z); o.w = f2b(v.w);
  reinterpret_cast<ushort4*>(out)[i] = o;
}

// ---------------- transpose+cast: in[R][C] f32 -> out[C][R] bf16 ----------------
__global__ void k_tcast(const float* __restrict__ in, u16* __restrict__ out, int R, int C) {
  __shared__ float tile[32][33];
  int c0 = blockIdx.x * 32, r0 = blockIdx.y * 32;
  int tx = threadIdx.x & 31, ty = threadIdx.x >> 5;
  #pragma unroll
  for (int rr = ty; rr < 32; rr += 8)
    tile[rr][tx] = in[(size_t)(r0 + rr) * C + c0 + tx];
  __syncthreads();
  #pragma unroll
  for (int cc = ty; cc < 32; cc += 8)
    out[(size_t)(c0 + cc) * R + r0 + tx] = f2b(tile[tx][cc]);
}

// ---------------- QKV GEMM: [8192,768] x [768,2304] + bias ----------------
// Epilogue: Q*scale -> [bh][t][64]; K,V -> fragment-ordered KV buffer:
//   KV[bh][kt(64-row tiles)][ K: frag(nf*2+kk)[lane=g*16+r][8]  (t=kt*64+nf*16+r, hd=kk*32+g*8+e)
//                           | V: 4096 + frag(hf*2+ks)[lane][8]  (hd=hf*16+r, tloc=ks*32+g*8+e) ]
__launch_bounds__(256, 3)
__global__ void k_gemm_qkv(const u16* __restrict__ A, const u16* __restrict__ Bt,
                           const float* __restrict__ bias,
                           u16* __restrict__ Qg, u16* __restrict__ KV)
{
  __shared__ u16 Al[128 * 32];
  __shared__ u16 Bl[128 * 32];
  const int tid = threadIdx.x, lane = tid & 63, wv = tid >> 6;
  const int g = lane >> 4, r = lane & 15;
  const int wm = (wv >> 1) * 64, wn = (wv & 1) * 64;
  // bijective XCD swizzle: nwg = 18*64 = 1152, 1152/8 = 144
  const int bid = blockIdx.x + blockIdx.y * 18;
  const int swz = (bid & 7) * 144 + (bid >> 3);
  const int m0 = (swz / 18) * 128, n0 = (swz % 18) * 128;
  const int srow = lane >> 2;
  const int scol = (lane & 3) * 8;
  f32x4 acc[4][4] = {};
  for (int k0 = 0; k0 < ND; k0 += 32) {
    __syncthreads();
    #pragma unroll
    for (int i = 0; i < 2; ++i) {
      int c = wv * 2 + i;
      gload16(&A[(size_t)(m0 + c * 16 + srow) * ND + k0 + scol], &Al[c * 512]);
      gload16(&Bt[(size_t)(n0 + c * 16 + srow) * ND + k0 + scol], &Bl[c * 512]);
    }
    __syncthreads();
    bf16x8 af[4], bfr[4];
    #pragma unroll
    for (int mf = 0; mf < 4; ++mf)
      af[mf] = *reinterpret_cast<const bf16x8*>(&Al[(wm + mf * 16 + r) * 32 + g * 8]);
    #pragma unroll
    for (int nf = 0; nf < 4; ++nf)
      bfr[nf] = *reinterpret_cast<const bf16x8*>(&Bl[(wn + nf * 16 + r) * 32 + g * 8]);
    #pragma unroll
    for (int mf = 0; mf < 4; ++mf)
      #pragma unroll
      for (int nf = 0; nf < 4; ++nf)
        acc[mf][nf] = __builtin_amdgcn_mfma_f32_16x16x32_bf16(af[mf], bfr[nf], acc[mf][nf], 0, 0, 0);
  }
  #pragma unroll
  for (int mf = 0; mf < 4; ++mf)
    #pragma unroll
    for (int nf = 0; nf < 4; ++nf) {
      int col = n0 + wn + nf * 16 + r;             // [0,2304)
      int which = col / ND, c = col - which * ND;  // uniform per fragment
      int h = c >> 6, hd = c & 63;
      int row0 = m0 + wm + mf * 16 + 4 * g;        // 4 consecutive t values
      int bb = row0 >> 10, t0 = row0 & 1023;
      size_t bh = (size_t)bb * NH + h;
      float b = bias[col];
      if (which == 0) {
        #pragma unroll
        for (int jj = 0; jj < 4; ++jj)
          Qg[(bh * NT + t0 + jj) * 64 + hd] = f2b((acc[mf][nf][jj] + b) * ATT_SCALE);
      } else if (which == 1) {
        int kt = t0 >> 6, nfk = (t0 >> 4) & 3, rk0 = t0 & 15;  // rk0 = 4*g
        int kk = hd >> 5, ghd = (hd >> 3) & 3, e = hd & 7;
        size_t base = (bh * 16 + kt) * 8192 + (size_t)(nfk * 2 + kk) * 512 + e;
        #pragma unroll
        for (int jj = 0; jj < 4; ++jj)
          KV[base + (ghd * 16 + rk0 + jj) * 8] = f2b(acc[mf][nf][jj] + b);
      } else {
        int kt = t0 >> 6, tl0 = t0 & 63;
        int ks = tl0 >> 5, gv = (tl0 >> 3) & 3, e0 = tl0 & 7;  // e0 in {0,4}
        int hf = hd >> 4, rv = hd & 15;
        size_t base = (bh * 16 + kt) * 8192 + 4096 +
                      (size_t)(hf * 2 + ks) * 512 + (gv * 16 + rv) * 8 + e0;
        ushort4 o;
        o.x = f2b(acc[mf][nf][0] + b);
        o.y = f2b(acc[mf][nf][1] + b);
        o.z = f2b(acc[mf][nf][2] + b);
        o.w = f2b(acc[mf][nf][3] + b);
        *reinterpret_cast<ushort4*>(&KV[base]) = o;
      }
    }
}

// ---------------- flash attention (fragment-ordered KV, 2-phase pipeline) ----------------
// block = (bh, qt): 4 waves x 32 q-rows; KV tiles of 64.
// S^T = mfma(K, Q): lane (g,r) holds S[k=nf*16+4g+jj][q=mf*16+r]
// O^T = mfma(V^T, P^T): lane (g,r) holds O[q=mf*16+r][hd=hf*16+4g+jj]
__launch_bounds__(256, 3)
__global__ void k_attn(const u16* __restrict__ Qg, const u16* __restrict__ KV,
                       u16* __restrict__ Ob)
{
  __shared__ u16 kv[2][8192];   // [buf][ K 4096 | V 4096 ] elems, fragment-ordered
  __shared__ u16 Pl[4][1024];   // per-wave P ping: [mf][lane][8] for one 32-k chunk
  const int tid = threadIdx.x, lane = tid & 63, wv = tid >> 6;
  const int g = lane >> 4, r = lane & 15;
  const int bh = blockIdx.x;  // fastest -> all qt of a bh share an XCD (96%8==0)
  const int qt = blockIdx.y;
  const int bb = bh / NH, h = bh - bb * NH;
  const u16* Qb = Qg + (size_t)bh * NT * 64;
  const u16* kvb = KV + (size_t)bh * 16 * 8192;

  bf16x8 qf[2][2];
  #pragma unroll
  for (int mf = 0; mf < 2; ++mf)
    #pragma unroll
    for (int kk = 0; kk < 2; ++kk) {
      int qrow = qt * 128 + wv * 32 + mf * 16 + r;
      qf[mf][kk] = *reinterpret_cast<const bf16x8*>(&Qb[(size_t)qrow * 64 + kk * 32 + g * 8]);
    }

  float mst[2] = {-1e30f, -1e30f}, lst[2] = {0.f, 0.f};
  f32x4 oacc[2][4] = {};

  const u16* srcbase = kvb + wv * 512 + lane * 8;
  // prologue: stage tile 0
  #pragma unroll
  for (int i = 0; i < 4; ++i)
    gload16(srcbase + i * 2048, &kv[0][wv * 512 + i * 2048]);
  asm volatile("s_waitcnt vmcnt(0)" ::: "memory");
  __syncthreads();

  for (int kt = 0; kt < 16; ++kt) {
    const int cur = kt & 1;
    if (kt < 15) {
      const u16* src = srcbase + (size_t)(kt + 1) * 8192;
      #pragma unroll
      for (int i = 0; i < 4; ++i)
        gload16(src + i * 2048, &kv[cur ^ 1][wv * 512 + i * 2048]);
    }
    const u16* Kb = kv[cur];
    const u16* Vb = kv[cur] + 4096;
    u16* Pw = Pl[wv];

    // S^T = K . Q^T  (Q pre-scaled)
    f32x4 st[2][4] = {};
    #pragma unroll
    for (int kk = 0; kk < 2; ++kk) {
      bf16x8 kf[4];
      #pragma unroll
      for (int nf = 0; nf < 4; ++nf)
        kf[nf] = *reinterpret_cast<const bf16x8*>(&Kb[(nf * 2 + kk) * 512 + lane * 8]);
      #pragma unroll
      for (int mf = 0; mf < 2; ++mf)
        #pragma unroll
        for (int nf = 0; nf < 4; ++nf)
          st[mf][nf] = __builtin_amdgcn_mfma_f32_16x16x32_bf16(kf[nf], qf[mf][kk], st[mf][nf], 0, 0, 0);
    }

    // online softmax: q = mf*16+r; lane holds 16 of 64 k-values; rest in lanes r^16, r^32, r^48
    #pragma unroll
    for (int mf = 0; mf < 2; ++mf) {
      float a0 = fmaxf(fmaxf(st[mf][0][0], st[mf][0][1]), fmaxf(st[mf][0][2], st[mf][0][3]));
      float a1 = fmaxf(fmaxf(st[mf][1][0], st[mf][1][1]), fmaxf(st[mf][1][2], st[mf][1][3]));
      float a2 = fmaxf(fmaxf(st[mf][2][0], st[mf][2][1]), fmaxf(st[mf][2][2], st[mf][2][3]));
      float a3 = fmaxf(fmaxf(st[mf][3][0], st[mf][3][1]), fmaxf(st[mf][3][2], st[mf][3][3]));
      float mx = fmaxf(fmaxf(a0, a1), fmaxf(a2, a3));
      mx = fmaxf(mx, __shfl_xor(mx, 16, 64));
      mx = fmaxf(mx, __shfl_xor(mx, 32, 64));
      float mnew = fmaxf(mst[mf], mx);
      float corr = __expf(mst[mf] - mnew);
      float rs = 0.f;
      #pragma unroll
      for (int nf = 0; nf < 4; ++nf)
        #pragma unroll
        for (int jj = 0; jj < 4; ++jj) {
          float p = __expf(st[mf][nf][jj] - mnew);
          st[mf][nf][jj] = p;
          rs += p;
        }
      rs += __shfl_xor(rs, 16, 64);
      rs += __shfl_xor(rs, 32, 64);
      mst[mf] = mnew;
      lst[mf] = lst[mf] * corr + rs;
      #pragma unroll
      for (int hf = 0; hf < 4; ++hf) oacc[mf][hf] *= corr;
    }

    // PV in two 32-k chunks through the wave-private fragment-ordered ping
    #pragma unroll
    for (int ks = 0; ks < 2; ++ks) {
      #pragma unroll
      for (int mf = 0; mf < 2; ++mf)
        #pragma unroll
        for (int u = 0; u < 2; ++u) {
          // k = (2ks+u)*16 + 4g + jj -> frag lane' = (u*2+(g>>1))*16 + r, elems (g&1)*4 + jj
          uint2 w;
          w.x = pk2(st[mf][2 * ks + u][0], st[mf][2 * ks + u][1]);
          w.y = pk2(st[mf][2 * ks + u][2], st[mf][2 * ks + u][3]);
          int gp = u * 2 + (g >> 1);
          *reinterpret_cast<uint2*>(&Pw[mf * 512 + (gp * 16 + r) * 8 + (g & 1) * 4]) = w;
        }
      bf16x8 pf[2], vf[4];
      #pragma unroll
      for (int mf = 0; mf < 2; ++mf)
        pf[mf] = *reinterpret_cast<const bf16x8*>(&Pw[mf * 512 + lane * 8]);
      #pragma unroll
      for (int hf = 0; hf < 4; ++hf)
        vf[hf] = *reinterpret_cast<const bf16x8*>(&Vb[(hf * 2 + ks) * 512 + lane * 8]);
      #pragma unroll
      for (int mf = 0; mf < 2; ++mf)
        #pragma unroll
        for (int hf = 0; hf < 4; ++hf)
          oacc[mf][hf] = __builtin_amdgcn_mfma_f32_16x16x32_bf16(vf[hf], pf[mf], oacc[mf][hf], 0, 0, 0);
    }

    asm volatile("s_waitcnt vmcnt(0)" ::: "memory");
    __syncthreads();
  }

  // normalize + store O as bf16 [B,T,H*64]; lane (g,r): q = mf*16+r, hd = hf*16+4g+jj
  #pragma unroll
  for (int mf = 0; mf < 2; ++mf) {
    float inv = 1.f / lst[mf];
    int row = qt * 128 + wv * 32 + mf * 16 + r;
    #pragma unroll
    for (int hf = 0; hf < 4; ++hf) {
      uint2 w;
      w.x = pk2(oacc[mf][hf][0] * inv, oacc[mf][hf][1] * inv);
      w.y = pk2(oacc[mf][hf][2] * inv, oacc[mf][hf][3] * inv);
      *reinterpret_cast<uint2*>(&Ob[((size_t)(bb * NT + row)) * ND + h * 64 + hf * 16 + 4 * g]) = w;
    }
  }
}

// ---------------- proj GEMM: [8192,768] x [768,768] + bias -> f32 out ----------------
__launch_bounds__(256, 3)
__global__ void k_gemm_proj(const u16* __restrict__ A, const u16* __restrict__ Bt,
                            const float* __restrict__ bias, float* __restrict__ out)
{
  __shared__ u16 Al[128 * 32];
  __shared__ u16 Bl[128 * 32];
  const int tid = threadIdx.x, lane = tid & 63, wv = tid >> 6;
  const int g = lane >> 4, r = lane & 15;
  const int wm = (wv >> 1) * 64, wn = (wv & 1) * 64;
  // bijective XCD swizzle: nwg = 6*64 = 384, 384/8 = 48
  const int bid = blockIdx.x + blockIdx.y * 6;
  const int swz = (bid & 7) * 48 + (bid >> 3);
  const int m0 = (swz / 6) * 128, n0 = (swz % 6) * 128;
  const int srow = lane >> 2;
  const int scol = (lane & 3) * 8;
  f32x4 acc[4][4] = {};
  for (int k0 = 0; k0 < ND; k0 += 32) {
    __syncthreads();
    #pragma unroll
    for (int i = 0; i < 2; ++i) {
      int c = wv * 2 + i;
      gload16(&A[(size_t)(m0 + c * 16 + srow) * ND + k0 + scol], &Al[c * 512]);
      gload16(&Bt[(size_t)(n0 + c * 16 + srow) * ND + k0 + scol], &Bl[c * 512]);
    }
    __syncthreads();
    bf16x8 af[4], bfr[4];
    #pragma unroll
    for (int mf = 0; mf < 4; ++mf)
      af[mf] = *reinterpret_cast<const bf16x8*>(&Al[(wm + mf * 16 + r) * 32 + g * 8]);
    #pragma unroll
    for (int nf = 0; nf < 4; ++nf)
      bfr[nf] = *reinterpret_cast<const bf16x8*>(&Bl[(wn + nf * 16 + r) * 32 + g * 8]);
    #pragma unroll
    for (int mf = 0; mf < 4; ++mf)
      #pragma unroll
      for (int nf = 0; nf < 4; ++nf)
        acc[mf][nf] = __builtin_amdgcn_mfma_f32_16x16x32_bf16(af[mf], bfr[nf], acc[mf][nf], 0, 0, 0);
  }
  #pragma unroll
  for (int mf = 0; mf < 4; ++mf)
    #pragma unroll
    for (int nf = 0; nf < 4; ++nf) {
      int col = n0 + wn + nf * 16 + r;
      float b = bias[col];
      #pragma unroll
      for (int jj = 0; jj < 4; ++jj) {
        int row = m0 + wm + mf * 16 + 4 * g + jj;
        out[(size_t)row * ND + col] = acc[mf][nf][jj] + b;
      }
    }
}

// ---------------- launch ----------------
extern "C" void kernel_launch(void* const* d_in, const int* in_sizes, int n_in,
                              void* d_out, int out_size, void* d_ws, size_t ws_size,
                              hipStream_t stream)
{
  const float* x     = (const float*)d_in[0];
  const float* Wqkv  = (const float*)d_in[1];
  const float* bqkv  = (const float*)d_in[2];
  const float* Wproj = (const float*)d_in[3];
  const float* bproj = (const float*)d_in[4];
  float* out = (float*)d_out;

  char* ws = (char*)d_ws;
  u16* xb  = (u16*)(ws + 0);          // 8192*768*2       = 12,582,912
  u16* wqt = (u16*)(ws + 12582912);   // 2304*768*2       =  3,538,944
  u16* wpt = (u16*)(ws + 16121856);   // 768*768*2        =  1,179,648
  u16* Qg  = (u16*)(ws + 17301504);   // 96*1024*64*2     = 12,582,912
  u16* KV  = (u16*)(ws + 29884416);   // 96*16*8192*2     = 25,165,824
  u16* Ob  = (u16*)(ws + 55050240);   // 12,582,912 -> ends 67,633,152

  k_cast<<<dim3((8192 * 768 / 4 + 255) / 256), dim3(256), 0, stream>>>(x, xb, 8192 * 768 / 4);
  k_tcast<<<dim3(2304 / 32, 768 / 32), dim3(256), 0, stream>>>(Wqkv, wqt, 768, 2304);
  k_tcast<<<dim3(768 / 32, 768 / 32), dim3(256), 0, stream>>>(Wproj, wpt, 768, 768);
  k_gemm_qkv<<<dim3(2304 / 128, 8192 / 128), dim3(256), 0, stream>>>(xb, wqt, bqkv, Qg, KV);
  k_attn<<<dim3(96, 8), dim3(256), 0, stream>>>(Qg, KV, Ob);
  k_gemm_proj<<<dim3(768 / 128, 8192 / 128), dim3(256), 0, stream>>>(Ob, wpt, bproj, out);
}